// Round 5
// baseline (332.030 us; speedup 1.0000x reference)
//
#include <hip/hip_runtime.h>
#include <stdint.h>

#define NB 8
#define NC 256
#define ND 32
#define NN 4096
#define QT 64    // queries per attention block
#define KT 32    // keys per iteration

typedef __attribute__((ext_vector_type(8))) short short8;
typedef __attribute__((ext_vector_type(4))) float float4_;

#define MFMA16(a,b,c) __builtin_amdgcn_mfma_f32_16x16x32_bf16((a),(b),(c),0,0,0)

#if __has_builtin(__builtin_amdgcn_exp2f)
#define EXP2(x) __builtin_amdgcn_exp2f(x)
#else
#define EXP2(x) exp2f(x)
#endif
#define L2E 1.44269504088896f
// fixed softmax max (log2 domain): logits |q.k| <= ~11 << 24, so exp2 arg
// stays in [-63,-5] -- no overflow/underflow, scale cancels in p.v/sum(p).
#define SCB (24.0f * L2E)

__device__ __forceinline__ uint16_t f2bf(float f) {
  uint32_t u = __builtin_bit_cast(uint32_t, f);
  u += 0x7fffu + ((u >> 16) & 1u);
  return (uint16_t)(u >> 16);
}
__device__ __forceinline__ float bf2f(uint16_t h) {
  uint32_t u = (uint32_t)h << 16;
  return __builtin_bit_cast(float, u);
}
__device__ __forceinline__ short8 ld8(const uint16_t* p) {
  return *reinterpret_cast<const short8*>(p);
}
// pack two f32 -> one u32 of 2x bf16 (RNE), single instruction
__device__ __forceinline__ uint32_t cvtpk(float lo, float hi) {
  uint32_t r;
  asm("v_cvt_pk_bf16_f32 %0, %1, %2" : "=v"(r) : "v"(lo), "v"(hi));
  return r;
}
// raw barrier with compiler memory fences on both sides (no vmcnt drain)
__device__ __forceinline__ void fbar() {
  asm volatile("" ::: "memory");
  __builtin_amdgcn_s_barrier();
  asm volatile("" ::: "memory");
}

// ---------------------------------------------------------------------------
// k_prep: VERBATIM (passed). x -> xTh/xTl; W -> Wh/Wl.
// ---------------------------------------------------------------------------
__global__ __launch_bounds__(256) void k_prep(
    const float* __restrict__ x, const float* __restrict__ wq,
    const float* __restrict__ wk, const float* __restrict__ wv,
    uint16_t* __restrict__ xTh, uint16_t* __restrict__ xTl,
    uint16_t* __restrict__ Wh, uint16_t* __restrict__ Wl, int use_xl)
{
  int bx = blockIdx.x, tid = threadIdx.x;
  if (bx >= 2048) {
    int e = (bx - 2048) * 256 + tid;
    int r = e >> 8;
    float w = (r < 32) ? wq[e] : (r < 64) ? wk[e - 32 * 256] : wv[e - 64 * 256];
    uint16_t h = f2bf(w);
    Wh[e] = h;
    Wl[e] = f2bf(w - bf2f(h));
    return;
  }
  __shared__ uint32_t tile[64][65];
  int b = bx >> 8, t = bx & 255;
  int c0 = (t >> 6) << 6, n0 = (t & 63) << 6;
  const float* xb = x + ((size_t)b * NC + c0) * NN + n0;
  int cc = tid >> 4, nw = (tid & 15) << 2;
  for (int i = 0; i < 4; i++) {
    int c = cc + 16 * i;
    float4_ v = *reinterpret_cast<const float4_*>(xb + (size_t)c * NN + nw);
    for (int u = 0; u < 4; u++) {
      uint16_t h = f2bf(v[u]);
      uint16_t l = f2bf(v[u] - bf2f(h));
      tile[c][nw + u] = (uint32_t)h | ((uint32_t)l << 16);
    }
  }
  __syncthreads();
  int cw = (tid & 15) << 2, nn = tid >> 4;
  for (int i = 0; i < 4; i++) {
    int n = nn + 16 * i;
    uint32_t p0 = tile[cw + 0][n], p1 = tile[cw + 1][n];
    uint32_t p2 = tile[cw + 2][n], p3 = tile[cw + 3][n];
    size_t o = ((size_t)b * NN + n0 + n) * NC + c0 + cw;
    *(uint32_t*)(xTh + o)     = (p0 & 0xffffu) | (p1 << 16);
    *(uint32_t*)(xTh + o + 2) = (p2 & 0xffffu) | (p3 << 16);
    if (use_xl) {
      *(uint32_t*)(xTl + o)     = (p0 >> 16) | (p1 & 0xffff0000u);
      *(uint32_t*)(xTl + o + 2) = (p2 >> 16) | (p3 & 0xffff0000u);
    }
  }
}

// ---------------------------------------------------------------------------
// k_qkv: VERBATIM (passed). Q in log2 domain.
// ---------------------------------------------------------------------------
__global__ __launch_bounds__(256) void k_qkv(
    const uint16_t* __restrict__ xTh, const uint16_t* __restrict__ xTl,
    const uint16_t* __restrict__ Wh, const uint16_t* __restrict__ Wl,
    const float* __restrict__ bq, const float* __restrict__ bk,
    const float* __restrict__ bv,
    uint16_t* __restrict__ Qh, uint16_t* __restrict__ Ql,
    uint16_t* __restrict__ Kh, uint16_t* __restrict__ Kl,
    uint16_t* __restrict__ V, int use_xl, int use_lo)
{
  int b = blockIdx.x & 7, n0 = (blockIdx.x >> 3) * 64;
  int tid = threadIdx.x, wid = tid >> 6, lane = tid & 63;
  int l15 = lane & 15, quad = lane >> 4;
  int nb = n0 + wid * 16;
  float4_ acc[20];
  for (int m = 0; m < 20; m++) acc[m] = (float4_){0.f, 0.f, 0.f, 0.f};
  for (int ks = 0; ks < 8; ks++) {
    size_t xa = ((size_t)b * NN + nb + l15) * NC + ks * 32 + quad * 8;
    short8 bh = ld8(xTh + xa);
    short8 blo;
    if (use_xl) blo = ld8(xTl + xa);
    for (int mt = 0; mt < 20; mt++) {
      size_t wa = (size_t)(16 * mt + l15) * NC + ks * 32 + quad * 8;
      short8 ah = ld8(Wh + wa);
      acc[mt] = MFMA16(ah, bh, acc[mt]);
      if (mt < 4) {
        short8 al = ld8(Wl + wa);
        acc[mt] = MFMA16(al, bh, acc[mt]);
      }
      if (use_xl) acc[mt] = MFMA16(ah, blo, acc[mt]);
    }
  }
  int n = nb + l15;
  for (int mt = 0; mt < 20; mt++) {
    for (int r = 0; r < 4; r++) {
      int row = 16 * mt + quad * 4 + r;
      float v = acc[mt][r];
      if (mt < 2) {
        v = (v + bq[row]) * L2E;      // log2-domain Q
        size_t o = ((size_t)b * NN + n) * ND + row;
        uint16_t h = f2bf(v);
        Qh[o] = h;
        if (use_lo) Ql[o] = f2bf(v - bf2f(h));
      } else if (mt < 4) {
        int rk = row - 32;
        v += bk[rk];
        size_t o = ((size_t)b * NN + n) * ND + rk;
        uint16_t h = f2bf(v);
        Kh[o] = h;
        if (use_lo) Kl[o] = f2bf(v - bf2f(h));
      } else {
        int c = row - 64;
        v += bv[c];
        V[((size_t)b * NC + c) * NN + n] = f2bf(v);
      }
    }
  }
}

// ---------------------------------------------------------------------------
// k_attn: R3 skeleton + V->register prefetch (the change under test).
//   512 blocks (8 b x 64 q-tiles of 64), 512 thr = 8 waves, 2 blocks/CU.
//   No sV, no staging waves: 8 symmetric waves. Wave (qtw=wid>>1, ktw=wid&1)
//   per 32-key iteration j (ONE barrier):
//     - QK^T(j+1): its 16q x 16k subtile (3 MFMA + 4 exp2 + uint2 sP write),
//       K frags loaded one iteration ahead (registers);
//     - K(j+2) frag loads issue (consumed next iter);
//     - PV(j): 4 sP ds_read_b128 + V frags FROM REGISTERS (vA/vB ping-pong,
//       loaded TWO iterations ahead; loop unrolled x2 for static reg indexing);
//     - V(j+2) loads issue after their regs are consumed;
//     - lgkmcnt(0); s_barrier.  Register loads need no barrier semantics and
//       stay in flight across it (compiler tracks data deps).
//   V (2 MB/batch) is L2-resident via bx&7 XCD pinning; per-lane V addresses:
//   4 lanes/quad cover contiguous 64B -> full 64B-line coalescing.
//   LDS 10.8 KB (sP ping-pong pitch-40 + sL). launch_bounds(512,4): VGPR<=128.
// ---------------------------------------------------------------------------
__global__ __launch_bounds__(512, 4) void k_attn(
    const uint16_t* __restrict__ Qh, const uint16_t* __restrict__ Ql,
    const uint16_t* __restrict__ Kh, const uint16_t* __restrict__ Kl,
    const uint16_t* __restrict__ V, float* __restrict__ out, int use_lo)
{
  __shared__ uint16_t sP[2][64][40];   // ping-pong P^T [buf][q][k], pitch 40
  __shared__ float sL[2][QT];          // [k-tile][q] softmax denom partials

  int bx = blockIdx.x;
  int b = bx & 7;                      // batch <-> XCD affinity
  int q0 = (bx >> 3) * QT;
  int tid = threadIdx.x, wid = tid >> 6, lane = tid & 63;
  int l15 = lane & 15, quad = lane >> 4;
  const size_t qkb = (size_t)b * NN * ND;
  const uint16_t* Vb = V + (size_t)b * NC * NN;
  const int qtw = wid >> 1;            // this wave's QK^T q-group (0..3)
  const int ktw = wid & 1;             // this wave's k-tile (0..1)

  // Q fragments (held for the whole kernel)
  size_t qa = qkb + (size_t)(q0 + qtw * 16 + l15) * ND + quad * 8;
  short8 qfh = ld8(Qh + qa), qfl;
  if (use_lo) qfl = ld8(Ql + qa);

  // K pointer for this wave's k-tile; advances 32 rows (=1024 elems) per iter
  const uint16_t* pKh = Kh + qkb + (size_t)(ktw * 16 + l15) * ND + quad * 8;
  const uint16_t* pKl = Kl + qkb + (size_t)(ktw * 16 + l15) * ND + quad * 8;

  float4_ acc[2][4];                   // [c-tile][q-group]
  for (int m = 0; m < 2; m++) for (int n = 0; n < 4; n++)
    acc[m][n] = (float4_){0.f, 0.f, 0.f, 0.f};
  float l_part = 0.f;

  // QK^T subtile -> sP[sb]; S rows = k (quad*4+r), cols = q (l15)
  auto qkt = [&](int sb, short8 h, short8 lo) {
    float4_ S = (float4_){0.f, 0.f, 0.f, 0.f};
    S = MFMA16(h, qfh, S);
    if (use_lo) {
      S = MFMA16(lo, qfh, S);
      S = MFMA16(h, qfl, S);
    }
    float p[4];
#pragma unroll
    for (int r = 0; r < 4; r++) p[r] = EXP2(S[r] - SCB);
    l_part += (p[0] + p[1]) + (p[2] + p[3]);
    uint2 w;
    w.x = cvtpk(p[0], p[1]);
    w.y = cvtpk(p[2], p[3]);
    *reinterpret_cast<uint2*>(&sP[sb][qtw * 16 + l15][ktw * 16 + 4 * quad]) = w;
  };

  // ---- prologue ----
  short8 kh, klo;
  {
    short8 h0 = ld8(pKh), lo0;
    if (use_lo) lo0 = ld8(pKl);
    qkt(0, h0, lo0);                   // QK^T(0) -> sP[0]
    kh = ld8(pKh + 1024);              // K(1)
    if (use_lo) klo = ld8(pKl + 1024);
    pKh += 2048; pKl += 2048;          // -> K(2)
  }
  // V ping-pong: vA = V(0), vB = V(1); each = 2 frags (c-tiles mt=0,1)
  const uint16_t* vp = Vb + (size_t)(wid * 32 + l15) * NN + quad * 8;
  short8 vA0 = ld8(vp),      vA1 = ld8(vp + 16 * NN);
  short8 vB0 = ld8(vp + 32), vB1 = ld8(vp + 32 + 16 * NN);
  vp += 64;                            // -> V(2)
  asm volatile("s_waitcnt lgkmcnt(0)" ::: "memory");
  fbar();                              // sP[0] ready

  const int NIT = NN / KT;             // 128
  for (int j = 0; j < NIT; j += 2) {
    // ---------- even sub-iter: pb=0, V from vA ----------
    {
      if (j < NIT - 1) qkt(1, kh, klo);            // QK^T(j+1) -> sP[1]
      if (j < NIT - 2) {                           // K(j+2)
        kh = ld8(pKh); if (use_lo) klo = ld8(pKl);
        pKh += 1024; pKl += 1024;
      }
      short8 bp0 = ld8(&sP[0][ 0 + l15][quad * 8]);
      short8 bp1 = ld8(&sP[0][16 + l15][quad * 8]);
      short8 bp2 = ld8(&sP[0][32 + l15][quad * 8]);
      short8 bp3 = ld8(&sP[0][48 + l15][quad * 8]);
      acc[0][0] = MFMA16(vA0, bp0, acc[0][0]);
      acc[0][1] = MFMA16(vA0, bp1, acc[0][1]);
      acc[0][2] = MFMA16(vA0, bp2, acc[0][2]);
      acc[0][3] = MFMA16(vA0, bp3, acc[0][3]);
      acc[1][0] = MFMA16(vA1, bp0, acc[1][0]);
      acc[1][1] = MFMA16(vA1, bp1, acc[1][1]);
      acc[1][2] = MFMA16(vA1, bp2, acc[1][2]);
      acc[1][3] = MFMA16(vA1, bp3, acc[1][3]);
      if (j < NIT - 2) {                           // V(j+2) -> vA
        vA0 = ld8(vp); vA1 = ld8(vp + 16 * NN); vp += 32;
      }
      asm volatile("s_waitcnt lgkmcnt(0)" ::: "memory");
      fbar();                                      // sP[1] ready
    }
    // ---------- odd sub-iter: pb=1, V from vB ----------
    {
      int j1 = j + 1;
      if (j1 < NIT - 1) qkt(0, kh, klo);           // QK^T(j1+1) -> sP[0]
      if (j1 < NIT - 2) {                          // K(j1+2)
        kh = ld8(pKh); if (use_lo) klo = ld8(pKl);
        pKh += 1024; pKl += 1024;
      }
      short8 bp0 = ld8(&sP[1][ 0 + l15][quad * 8]);
      short8 bp1 = ld8(&sP[1][16 + l15][quad * 8]);
      short8 bp2 = ld8(&sP[1][32 + l15][quad * 8]);
      short8 bp3 = ld8(&sP[1][48 + l15][quad * 8]);
      acc[0][0] = MFMA16(vB0, bp0, acc[0][0]);
      acc[0][1] = MFMA16(vB0, bp1, acc[0][1]);
      acc[0][2] = MFMA16(vB0, bp2, acc[0][2]);
      acc[0][3] = MFMA16(vB0, bp3, acc[0][3]);
      acc[1][0] = MFMA16(vB1, bp0, acc[1][0]);
      acc[1][1] = MFMA16(vB1, bp1, acc[1][1]);
      acc[1][2] = MFMA16(vB1, bp2, acc[1][2]);
      acc[1][3] = MFMA16(vB1, bp3, acc[1][3]);
      if (j1 < NIT - 2) {                          // V(j1+2) -> vB
        vB0 = ld8(vp); vB1 = ld8(vp + 16 * NN); vp += 32;
      }
      asm volatile("s_waitcnt lgkmcnt(0)" ::: "memory");
      fbar();                                      // sP[0] ready
    }
  }

  // softmax denominators: wave (qtw,ktw) holds partials for q = qtw*16+l15
  float l_tot = l_part;
  l_tot += __shfl_xor(l_tot, 16);
  l_tot += __shfl_xor(l_tot, 32);
  if (quad == 0) sL[ktw][qtw * 16 + l15] = l_tot;
  __syncthreads();
  float linv[4];
#pragma unroll
  for (int qt = 0; qt < 4; qt++)
    linv[qt] = 1.0f / (sL[0][qt * 16 + l15] + sL[1][qt * 16 + l15]);
#pragma unroll
  for (int mt = 0; mt < 2; mt++)
#pragma unroll
    for (int qt = 0; qt < 4; qt++)
#pragma unroll
      for (int r = 0; r < 4; r++) {
        int c = wid * 32 + 16 * mt + quad * 4 + r;
        int q = q0 + qt * 16 + l15;
        out[((size_t)(b * NC + c)) * NN + q] = acc[mt][qt][r] * linv[qt];
      }
}

// ---------------------------------------------------------------------------
extern "C" void kernel_launch(void* const* d_in, const int* in_sizes, int n_in,
                              void* d_out, int out_size, void* d_ws, size_t ws_size,
                              hipStream_t stream)
{
  const float* x  = (const float*)d_in[0];
  const float* wq = (const float*)d_in[1];
  const float* bq = (const float*)d_in[2];
  const float* wk = (const float*)d_in[3];
  const float* bk = (const float*)d_in[4];
  const float* wv = (const float*)d_in[5];
  const float* bv = (const float*)d_in[6];
  float* out = (float*)d_out;

  const size_t szXT = (size_t)NB * NN * NC * 2;
  const size_t szW  = (size_t)320 * 256 * 2;
  const size_t szQK = (size_t)NB * NN * ND * 2;
  const size_t szV  = (size_t)NB * NC * NN * 2;
  size_t needA = 2 * szXT + 2 * szW + 4 * szQK + szV;
  size_t needB = szXT + 2 * szW + 4 * szQK + szV;
  int use_xl = ws_size >= needA;
  int use_lo = ws_size >= needB;

  char* p = (char*)d_ws;
  uint16_t* xTh = (uint16_t*)p; p += szXT;
  uint16_t* xTl = use_xl ? (uint16_t*)p : xTh; if (use_xl) p += szXT;
  uint16_t* Wh = (uint16_t*)p; p += szW;
  uint16_t* Wl = (uint16_t*)p; p += szW;
  uint16_t* Qh = (uint16_t*)p; p += szQK;
  uint16_t* Ql = use_lo ? (uint16_t*)p : xTh; if (use_lo) p += szQK;
  uint16_t* Kh = (uint16_t*)p; p += szQK;
  uint16_t* Kl = use_lo ? (uint16_t*)p : xTh; if (use_lo) p += szQK;
  uint16_t* Vw = (uint16_t*)p;

  hipLaunchKernelGGL(k_prep, dim3(2368), dim3(256), 0, stream,
                     x, wq, wk, wv, xTh, xTl, Wh, Wl, use_xl);
  hipLaunchKernelGGL(k_qkv, dim3(512), dim3(256), 0, stream,
                     xTh, xTl, Wh, Wl, bq, bk, bv, Qh, Ql, Kh, Kl, Vw,
                     use_xl, use_lo);
  hipLaunchKernelGGL(k_attn, dim3(512), dim3(512), 0, stream,
                     Qh, Ql, Kh, Kl, Vw, out, use_lo);
}

// Round 6
// 246.614 us; speedup vs baseline: 1.3464x; 1.3464x over previous
//
#include <hip/hip_runtime.h>
#include <stdint.h>

#define NB 8
#define NC 256
#define ND 32
#define NN 4096
#define QT 64    // queries per attention block
#define KT 32    // keys per iteration
#define NBUF 4   // V ring depth (single-barrier pipeline needs distance 3)

typedef __attribute__((ext_vector_type(8))) short short8;
typedef __attribute__((ext_vector_type(4))) float float4_;

#define MFMA16(a,b,c) __builtin_amdgcn_mfma_f32_16x16x32_bf16((a),(b),(c),0,0,0)

#if __has_builtin(__builtin_amdgcn_exp2f)
#define EXP2(x) __builtin_amdgcn_exp2f(x)
#else
#define EXP2(x) exp2f(x)
#endif
#define L2E 1.44269504088896f
// fixed softmax max (log2 domain): logits |q.k| <= ~11 << 24, so exp2 arg
// stays in [-63,-5] -- no overflow/underflow, scale cancels in p.v/sum(p).
#define SCB (24.0f * L2E)

__device__ __forceinline__ uint16_t f2bf(float f) {
  uint32_t u = __builtin_bit_cast(uint32_t, f);
  u += 0x7fffu + ((u >> 16) & 1u);
  return (uint16_t)(u >> 16);
}
__device__ __forceinline__ float bf2f(uint16_t h) {
  uint32_t u = (uint32_t)h << 16;
  return __builtin_bit_cast(float, u);
}
__device__ __forceinline__ short8 ld8(const uint16_t* p) {
  return *reinterpret_cast<const short8*>(p);
}
// pack two f32 -> one u32 of 2x bf16 (RNE), single instruction
__device__ __forceinline__ uint32_t cvtpk(float lo, float hi) {
  uint32_t r;
  asm("v_cvt_pk_bf16_f32 %0, %1, %2" : "=v"(r) : "v"(lo), "v"(hi));
  return r;
}
__device__ __forceinline__ void async16(const uint16_t* g, uint16_t* l) {
  __builtin_amdgcn_global_load_lds(
      (const __attribute__((address_space(1))) uint32_t*)g,
      (__attribute__((address_space(3))) uint32_t*)l, 16, 0, 0);
}
// raw barrier with compiler memory fences on both sides (no vmcnt drain)
__device__ __forceinline__ void fbar() {
  asm volatile("" ::: "memory");
  __builtin_amdgcn_s_barrier();
  asm volatile("" ::: "memory");
}

// ---------------------------------------------------------------------------
// k_prep: x -> xTh/xTl (verbatim); W -> PADDED SLICE layout (changed):
//   WhP[ks][row 0..319][40] (col 0..31 data, 32..39 pad)   -- 204800 B
//   WlP[ks][row 0..63 ][40] (low-order bf16 of QK rows)    --  40960 B
// so k_qkv can stage a ks-slice with a LINEAR global_load_lds copy while
// the LDS read pitch (40 halfwords) stays the proven 2-way-free pattern.
// ---------------------------------------------------------------------------
__global__ __launch_bounds__(256) void k_prep(
    const float* __restrict__ x, const float* __restrict__ wq,
    const float* __restrict__ wk, const float* __restrict__ wv,
    uint16_t* __restrict__ xTh, uint16_t* __restrict__ xTl,
    uint16_t* __restrict__ WhP, uint16_t* __restrict__ WlP, int use_xl)
{
  int bx = blockIdx.x, tid = threadIdx.x;
  if (bx >= 2048) {
    int e = (bx - 2048) * 256 + tid;
    int row = e >> 8, col = e & 255;
    float w = (row < 32) ? wq[e] : (row < 64) ? wk[e - 32 * 256]
                                              : wv[e - 64 * 256];
    uint16_t h = f2bf(w);
    int ks = col >> 5, c5 = col & 31;
    WhP[(size_t)ks * 12800 + row * 40 + c5] = h;
    if (row < 64)
      WlP[(size_t)ks * 2560 + row * 40 + c5] = f2bf(w - bf2f(h));
    return;
  }
  __shared__ uint32_t tile[64][65];
  int b = bx >> 8, t = bx & 255;
  int c0 = (t >> 6) << 6, n0 = (t & 63) << 6;
  const float* xb = x + ((size_t)b * NC + c0) * NN + n0;
  int cc = tid >> 4, nw = (tid & 15) << 2;
  for (int i = 0; i < 4; i++) {
    int c = cc + 16 * i;
    float4_ v = *reinterpret_cast<const float4_*>(xb + (size_t)c * NN + nw);
    for (int u = 0; u < 4; u++) {
      uint16_t h = f2bf(v[u]);
      uint16_t l = f2bf(v[u] - bf2f(h));
      tile[c][nw + u] = (uint32_t)h | ((uint32_t)l << 16);
    }
  }
  __syncthreads();
  int cw = (tid & 15) << 2, nn = tid >> 4;
  for (int i = 0; i < 4; i++) {
    int n = nn + 16 * i;
    uint32_t p0 = tile[cw + 0][n], p1 = tile[cw + 1][n];
    uint32_t p2 = tile[cw + 2][n], p3 = tile[cw + 3][n];
    size_t o = ((size_t)b * NN + n0 + n) * NC + c0 + cw;
    *(uint32_t*)(xTh + o)     = (p0 & 0xffffu) | (p1 << 16);
    *(uint32_t*)(xTh + o + 2) = (p2 & 0xffffu) | (p3 << 16);
    if (use_xl) {
      *(uint32_t*)(xTl + o)     = (p0 >> 16) | (p1 & 0xffff0000u);
      *(uint32_t*)(xTl + o + 2) = (p2 >> 16) | (p3 & 0xffff0000u);
    }
  }
}

// ---------------------------------------------------------------------------
// k_qkv: W staged through LDS (the change under test).
//   Old version issued 24 dependent global W loads per wave per ks, 1:1 with
//   MFMAs -> exposed L2 latency at 2 waves/SIMD dominated (est ~110 us).
//   Now: per ks-slice, all 256 threads stage WhP/WlP (30720 B = 1920 chunks
//   of 16 B; 8 guarded linear global_load_lds issues per thread) into a
//   double-buffered sW while computing from the other buffer; W reads become
//   ds_read_b128 at pitch 40 (2-way bank aliasing = free). xT loads (2/wave/
//   ks) rotate one ks ahead. 8 __syncthreads total. LDS 61440 B -> 2 blk/CU.
// ---------------------------------------------------------------------------
__global__ __launch_bounds__(256) void k_qkv(
    const uint16_t* __restrict__ xTh, const uint16_t* __restrict__ xTl,
    const uint16_t* __restrict__ WhP, const uint16_t* __restrict__ WlP,
    const float* __restrict__ bq, const float* __restrict__ bk,
    const float* __restrict__ bv,
    uint16_t* __restrict__ Qh, uint16_t* __restrict__ Ql,
    uint16_t* __restrict__ Kh, uint16_t* __restrict__ Kl,
    uint16_t* __restrict__ V, int use_xl, int use_lo)
{
  __shared__ uint16_t sW[2][15360];   // per buf: Wh slice [320][40] + Wl [64][40]

  int b = blockIdx.x & 7, n0 = (blockIdx.x >> 3) * 64;
  int tid = threadIdx.x, wid = tid >> 6, lane = tid & 63;
  int l15 = lane & 15, quad = lane >> 4;
  int nb = n0 + wid * 16;

  auto stageW = [&](int ks, int buf) {
    const uint16_t* srcH = WhP + (size_t)ks * 12800;
    const uint16_t* srcL = WlP + (size_t)ks * 2560;
    uint16_t* dst = &sW[buf][0];
#pragma unroll
    for (int i = 0; i < 8; i++) {
      int idx = i * 256 + tid;             // 16B-chunk index, 0..1919
      if (idx < 1920) {
        const uint16_t* g = (idx < 1600) ? (srcH + (size_t)idx * 8)
                                         : (srcL + (size_t)(idx - 1600) * 8);
        async16(g, dst + (size_t)idx * 8); // dest = uniform base + lane*16
      }
    }
  };

  float4_ acc[20];
  for (int m = 0; m < 20; m++) acc[m] = (float4_){0.f, 0.f, 0.f, 0.f};

  // xT fragment for ks=0 (rotated one ks ahead in the loop)
  size_t xa0 = ((size_t)b * NN + nb + l15) * NC + quad * 8;
  short8 bh = ld8(xTh + xa0), blo;
  if (use_xl) blo = ld8(xTl + xa0);

  stageW(0, 0);
  __syncthreads();                         // sW[0] ready

  for (int ks = 0; ks < 8; ks++) {
    int buf = ks & 1;
    if (ks < 7) stageW(ks + 1, buf ^ 1);   // fire-and-forget into other buf
    short8 nbh, nblo;
    if (ks < 7) {
      size_t xn = xa0 + (size_t)(ks + 1) * 32;
      nbh = ld8(xTh + xn);
      if (use_xl) nblo = ld8(xTl + xn);
    }
    const uint16_t* wb = &sW[buf][0];
#pragma unroll
    for (int mt = 0; mt < 20; mt++) {
      short8 ah = ld8(wb + (16 * mt + l15) * 40 + quad * 8);
      acc[mt] = MFMA16(ah, bh, acc[mt]);
      if (mt < 4) {
        short8 al = ld8(wb + 12800 + (16 * mt + l15) * 40 + quad * 8);
        acc[mt] = MFMA16(al, bh, acc[mt]);
      }
      if (use_xl) acc[mt] = MFMA16(ah, blo, acc[mt]);
    }
    __syncthreads();                       // stage(ks+1) landed; reads retired
    bh = nbh;
    if (use_xl) blo = nblo;
  }

  int n = nb + l15;
  for (int mt = 0; mt < 20; mt++) {
    for (int r = 0; r < 4; r++) {
      int row = 16 * mt + quad * 4 + r;
      float v = acc[mt][r];
      if (mt < 2) {
        v = (v + bq[row]) * L2E;      // log2-domain Q
        size_t o = ((size_t)b * NN + n) * ND + row;
        uint16_t h = f2bf(v);
        Qh[o] = h;
        if (use_lo) Ql[o] = f2bf(v - bf2f(h));
      } else if (mt < 4) {
        int rk = row - 32;
        v += bk[rk];
        size_t o = ((size_t)b * NN + n) * ND + rk;
        uint16_t h = f2bf(v);
        Kh[o] = h;
        if (use_lo) Kl[o] = f2bf(v - bf2f(h));
      } else {
        int c = row - 64;
        v += bv[c];
        V[((size_t)b * NC + c) * NN + n] = f2bf(v);
      }
    }
  }
}

// ---------------------------------------------------------------------------
// k_attn: VERBATIM R3 (139 us, passed): single-barrier software pipeline.
//   512 blocks (8 b x 64 q-tiles of 64), 512 thr = 8 waves, 2 blocks/CU.
//   Per phase j (ONE barrier at the end):
//     heavy (waves 0-3): prefetch K(j+2) regs; QK^T(j+1) -> sP[(j+1)&1];
//                        then PV(j).
//     light (waves 4-7): stage V(j+3) into buf (j+3)&3 (NBUF=4); then PV(j);
//                        vmcnt(8) keeps 2 stages in flight across the barrier.
// ---------------------------------------------------------------------------
__global__ __launch_bounds__(512, 4) void k_attn(
    const uint16_t* __restrict__ Qh, const uint16_t* __restrict__ Ql,
    const uint16_t* __restrict__ Kh, const uint16_t* __restrict__ Kl,
    const uint16_t* __restrict__ V, float* __restrict__ out, int use_lo)
{
  __shared__ uint16_t sV[NBUF][256][KT];  // 64 KB, chunk-swizzled
  __shared__ uint16_t sP[2][4][16][40];   // dbuf P^T [buf][qgroup][q][k]
  __shared__ float sL[QT];

  int bx = blockIdx.x;
  int b = bx & 7;                         // batch <-> XCD affinity
  int q0 = (bx >> 3) * QT;
  int tid = threadIdx.x, wid = tid >> 6, lane = tid & 63;
  int l15 = lane & 15, quad = lane >> 4;
  const size_t qkb = (size_t)b * NN * ND;
  const uint16_t* Vb = V + (size_t)b * NC * NN;
  const bool heavy = (wid < 4);

  int sw = (l15 >> 1) & 3;                // read-side swizzle key

  // ---- light-wave staging state: hoisted incremental pointers ----
  const uint16_t* gp0; const uint16_t* gp1;
  const uint16_t* gp2; const uint16_t* gp3;
  uint32_t off0, off1, off2, off3;
  if (!heavy) {
#define INITGP(i, GP, OFF)                                   \
    { int sl = (wid - 4) * 256 + 64 * i + lane;              \
      int c = sl >> 2;                                       \
      int q2s = (sl & 3) ^ ((sl >> 3) & 3);                  \
      GP = Vb + (size_t)c * NN + q2s * 8;                    \
      OFF = (uint32_t)(((wid - 4) * 4 + i) * 512); }
    INITGP(0, gp0, off0) INITGP(1, gp1, off1)
    INITGP(2, gp2, off2) INITGP(3, gp3, off3)
#undef INITGP
  }
  auto stage = [&](int s) {
    uint16_t* base = &sV[0][0][0] + (size_t)(s & 3) * 8192;
    async16(gp0, base + off0); gp0 += KT;
    async16(gp1, base + off1); gp1 += KT;
    async16(gp2, base + off2); gp2 += KT;
    async16(gp3, base + off3); gp3 += KT;
  };

  float4_ acc[2][4];                      // [c-tile][q-group]
  for (int m = 0; m < 2; m++) for (int n = 0; n < 4; n++)
    acc[m][n] = (float4_){0.f, 0.f, 0.f, 0.f};
  float l_part = 0.f;

  short8 qfh, qfl, kh0, kh1, kl0, kl1;
  const uint16_t* pKh = Kh + qkb + (size_t)l15 * ND + quad * 8;
  const uint16_t* pKl = Kl + qkb + (size_t)l15 * ND + quad * 8;

  // QK^T for key-tile index t, writing sP[sb][wid]
  auto qkt = [&](int sb, short8 h0, short8 h1, short8 lo0, short8 lo1) {
    float4_ S0 = (float4_){0.f, 0.f, 0.f, 0.f}, S1 = S0;
    S0 = MFMA16(h0, qfh, S0);
    S1 = MFMA16(h1, qfh, S1);
    if (use_lo) {
      S0 = MFMA16(lo0, qfh, S0); S0 = MFMA16(h0, qfl, S0);
      S1 = MFMA16(lo1, qfh, S1); S1 = MFMA16(h1, qfl, S1);
    }
    float p0[4], p1[4];
#pragma unroll
    for (int r = 0; r < 4; r++) {
      p0[r] = EXP2(S0[r] - SCB);
      p1[r] = EXP2(S1[r] - SCB);
    }
    l_part += ((p0[0] + p0[1]) + (p0[2] + p0[3])) +
              ((p1[0] + p1[1]) + (p1[2] + p1[3]));
    uint2 w0, w1;
    w0.x = cvtpk(p0[0], p0[1]); w0.y = cvtpk(p0[2], p0[3]);
    w1.x = cvtpk(p1[0], p1[1]); w1.y = cvtpk(p1[2], p1[3]);
    *reinterpret_cast<uint2*>(&sP[sb][wid][l15][4 * quad]) = w0;
    *reinterpret_cast<uint2*>(&sP[sb][wid][l15][16 + 4 * quad]) = w1;
  };

  // ---- prologue ----
  if (heavy) {
    size_t a = qkb + (size_t)(q0 + wid * 16 + l15) * ND + quad * 8;
    qfh = ld8(Qh + a);
    if (use_lo) qfl = ld8(Ql + a);
    // K(0): compute QK^T(0) -> sP[0]
    short8 t0 = ld8(pKh), t1 = ld8(pKh + 512), tl0, tl1;
    if (use_lo) { tl0 = ld8(pKl); tl1 = ld8(pKl + 512); }
    qkt(0, t0, t1, tl0, tl1);
    // K(1) -> current frags (consumed by QK^T(1) in phase 0)
    kh0 = ld8(pKh + 1024); kh1 = ld8(pKh + 1536);
    if (use_lo) { kl0 = ld8(pKl + 1024); kl1 = ld8(pKl + 1536); }
    pKh += 2048; pKl += 2048;             // -> K(2)
    asm volatile("s_waitcnt lgkmcnt(0)" ::: "memory");  // sP[0] visible
  } else {
    stage(0); stage(1); stage(2);
    asm volatile("s_waitcnt vmcnt(8)" ::: "memory");    // stage(0) landed
  }
  fbar();                                 // sP[0] + sV buf0 ready

  for (int j = 0; j < NN / KT; j++) {
    int buf = j & 3;
    int pb = j & 1;
    if (heavy) {
      short8 nh0, nh1, nl0, nl1;
      if (j < NN / KT - 2) {              // prefetch K(j+2)
        nh0 = ld8(pKh); nh1 = ld8(pKh + 512);
        if (use_lo) { nl0 = ld8(pKl); nl1 = ld8(pKl + 512); }
        pKh += 1024; pKl += 1024;
      }
      if (j < NN / KT - 1)                // QK^T(j+1) -> sP[(j+1)&1]
        qkt(pb ^ 1, kh0, kh1, kl0, kl1);
      kh0 = nh0; kh1 = nh1;
      if (use_lo) { kl0 = nl0; kl1 = nl1; }
    } else {
      if (j < NN / KT - 3) stage(j + 3);  // buf (j+3)&3: readers at j-1 done
    }
    // PV(j): all waves, 32 channels x 64 q
    short8 bfP[4];
#pragma unroll
    for (int qt = 0; qt < 4; qt++)
      bfP[qt] = ld8(&sP[pb][qt][l15][quad * 8]);
#pragma unroll
    for (int mt = 0; mt < 2; mt++) {
      short8 af = ld8(&sV[buf][wid * 32 + 16 * mt + l15][(quad ^ sw) * 8]);
#pragma unroll
      for (int qt = 0; qt < 4; qt++)
        acc[mt][qt] = MFMA16(af, bfP[qt], acc[mt][qt]);
    }
    if (!heavy) {
      if (j < NN / KT - 3)
        asm volatile("s_waitcnt vmcnt(8)" ::: "memory");  // stage(j+1) landed
      else
        asm volatile("s_waitcnt vmcnt(0)" ::: "memory");  // tail drain
    }
    // all LDS ops (sP write + PV reads) retired before anyone reuses buffers
    asm volatile("s_waitcnt lgkmcnt(0)" ::: "memory");
    fbar();
  }

  if (heavy) {
    float l_tot = l_part;
    l_tot += __shfl_xor(l_tot, 16);
    l_tot += __shfl_xor(l_tot, 32);
    if (quad == 0) sL[wid * 16 + l15] = l_tot;
  }
  __syncthreads();
  float linv[4];
  for (int qt = 0; qt < 4; qt++) linv[qt] = 1.0f / sL[qt * 16 + l15];
  for (int mt = 0; mt < 2; mt++)
    for (int qt = 0; qt < 4; qt++)
      for (int r = 0; r < 4; r++) {
        int c = wid * 32 + 16 * mt + quad * 4 + r;
        int q = q0 + qt * 16 + l15;
        out[((size_t)(b * NC + c)) * NN + q] = acc[mt][qt][r] * linv[qt];
      }
}

// ---------------------------------------------------------------------------
extern "C" void kernel_launch(void* const* d_in, const int* in_sizes, int n_in,
                              void* d_out, int out_size, void* d_ws, size_t ws_size,
                              hipStream_t stream)
{
  const float* x  = (const float*)d_in[0];
  const float* wq = (const float*)d_in[1];
  const float* bq = (const float*)d_in[2];
  const float* wk = (const float*)d_in[3];
  const float* bk = (const float*)d_in[4];
  const float* wv = (const float*)d_in[5];
  const float* bv = (const float*)d_in[6];
  float* out = (float*)d_out;

  const size_t szXT = (size_t)NB * NN * NC * 2;
  const size_t szWh = (size_t)8 * 320 * 40 * 2;   // padded slice layout
  const size_t szWl = (size_t)8 * 64 * 40 * 2;
  const size_t szQK = (size_t)NB * NN * ND * 2;
  const size_t szV  = (size_t)NB * NC * NN * 2;
  size_t needA = 2 * szXT + szWh + szWl + 4 * szQK + szV;
  size_t needB = szXT + szWh + szWl + 4 * szQK + szV;
  int use_xl = ws_size >= needA;
  int use_lo = ws_size >= needB;

  char* p = (char*)d_ws;
  uint16_t* xTh = (uint16_t*)p; p += szXT;
  uint16_t* xTl = use_xl ? (uint16_t*)p : xTh; if (use_xl) p += szXT;
  uint16_t* WhP = (uint16_t*)p; p += szWh;
  uint16_t* WlP = (uint16_t*)p; p += szWl;
  uint16_t* Qh = (uint16_t*)p; p += szQK;
  uint16_t* Ql = use_lo ? (uint16_t*)p : xTh; if (use_lo) p += szQK;
  uint16_t* Kh = (uint16_t*)p; p += szQK;
  uint16_t* Kl = use_lo ? (uint16_t*)p : xTh; if (use_lo) p += szQK;
  uint16_t* Vw = (uint16_t*)p;

  hipLaunchKernelGGL(k_prep, dim3(2368), dim3(256), 0, stream,
                     x, wq, wk, wv, xTh, xTl, WhP, WlP, use_xl);
  hipLaunchKernelGGL(k_qkv, dim3(512), dim3(256), 0, stream,
                     xTh, xTl, WhP, WlP, bq, bk, bv, Qh, Ql, Kh, Kl, Vw,
                     use_xl, use_lo);
  hipLaunchKernelGGL(k_attn, dim3(512), dim3(512), 0, stream,
                     Qh, Ql, Kh, Kl, Vw, out, use_lo);
}

// Round 7
// 235.694 us; speedup vs baseline: 1.4087x; 1.0463x over previous
//
#include <hip/hip_runtime.h>
#include <stdint.h>

#define NB 8
#define NC 256
#define ND 32
#define NN 4096
#define QT 64    // queries per attention block
#define KT 32    // keys per iteration
#define NBUF 4   // V ring depth (single-barrier pipeline needs distance 3)

typedef __attribute__((ext_vector_type(8))) short short8;
typedef __attribute__((ext_vector_type(4))) float float4_;
typedef __attribute__((ext_vector_type(4))) unsigned int uint4_;

#define MFMA16(a,b,c) __builtin_amdgcn_mfma_f32_16x16x32_bf16((a),(b),(c),0,0,0)

#if __has_builtin(__builtin_amdgcn_exp2f)
#define EXP2(x) __builtin_amdgcn_exp2f(x)
#else
#define EXP2(x) exp2f(x)
#endif
#define L2E 1.44269504088896f
// fixed softmax max (log2 domain): logits |q.k| <= ~11 << 24, so exp2 arg
// stays in [-63,-5] -- no overflow/underflow, scale cancels in p.v/sum(p).
#define SCB (24.0f * L2E)

__device__ __forceinline__ uint16_t f2bf(float f) {
  uint32_t u = __builtin_bit_cast(uint32_t, f);
  u += 0x7fffu + ((u >> 16) & 1u);
  return (uint16_t)(u >> 16);
}
__device__ __forceinline__ float bf2f(uint16_t h) {
  uint32_t u = (uint32_t)h << 16;
  return __builtin_bit_cast(float, u);
}
__device__ __forceinline__ short8 ld8(const uint16_t* p) {
  return *reinterpret_cast<const short8*>(p);
}
// pack two f32 -> one u32 of 2x bf16 (RNE), single instruction
__device__ __forceinline__ uint32_t cvtpk(float lo, float hi) {
  uint32_t r;
  asm("v_cvt_pk_bf16_f32 %0, %1, %2" : "=v"(r) : "v"(lo), "v"(hi));
  return r;
}
__device__ __forceinline__ void async16(const uint16_t* g, uint16_t* l) {
  __builtin_amdgcn_global_load_lds(
      (const __attribute__((address_space(1))) uint32_t*)g,
      (__attribute__((address_space(3))) uint32_t*)l, 16, 0, 0);
}
// raw barrier with compiler memory fences on both sides (no vmcnt drain)
__device__ __forceinline__ void fbar() {
  asm volatile("" ::: "memory");
  __builtin_amdgcn_s_barrier();
  asm volatile("" ::: "memory");
}

// ---------------------------------------------------------------------------
// k_prep: W-branch only (x transpose moved INTO k_qkv). 320 blocks x 256.
//   Writes padded slice layout:
//   WhP[ks][row 0..319][40] (col 0..31 data, 32..39 pad)   -- 204800 B
//   WlP[ks][row 0..63 ][40] (low-order bf16 of QK rows)    --  40960 B
// ---------------------------------------------------------------------------
__global__ __launch_bounds__(256) void k_prep(
    const float* __restrict__ wq, const float* __restrict__ wk,
    const float* __restrict__ wv,
    uint16_t* __restrict__ WhP, uint16_t* __restrict__ WlP)
{
  int e = blockIdx.x * 256 + threadIdx.x;
  int row = e >> 8, col = e & 255;
  float w = (row < 32) ? wq[e] : (row < 64) ? wk[e - 32 * 256]
                                            : wv[e - 64 * 256];
  uint16_t h = f2bf(w);
  int ks = col >> 5, c5 = col & 31;
  WhP[(size_t)ks * 12800 + row * 40 + c5] = h;
  if (row < 64)
    WlP[(size_t)ks * 2560 + row * 40 + c5] = f2bf(w - bf2f(h));
}

// ---------------------------------------------------------------------------
// k_qkv: FUSED transpose + GEMM (the change under test).
//   Deletes the 64 MB xTh/xTl HBM round-trip: each block (b, n0) reads its
//   x[b][:][n0..n0+63] slice directly (f32, 256-B coalesced segments),
//   transposes + bf16-splits into a packed LDS tile xt[64 n][132 c-half]
//   (uint32 = h | l<<16; two 128-channel halves), and feeds MFMA B-frags
//   from LDS: 2 ds_read_b128 + 16 bit-ops replace 2 global xT loads.
//   W staged per ks-slice as in R6 (single-buffered: stage -> barrier ->
//   compute -> barrier; first stage overlaps the transpose).
//   xt row stride 132 dwords (528 B, 16B-aligned for b128).
//   LDS: 33792 (xt) + 30720 (sW) = 64512 B -> 2 blocks/CU.
// ---------------------------------------------------------------------------
__global__ __launch_bounds__(256) void k_qkv(
    const float* __restrict__ x,
    const uint16_t* __restrict__ WhP, const uint16_t* __restrict__ WlP,
    const float* __restrict__ bq, const float* __restrict__ bk,
    const float* __restrict__ bv,
    uint16_t* __restrict__ Qh, uint16_t* __restrict__ Ql,
    uint16_t* __restrict__ Kh, uint16_t* __restrict__ Kl,
    uint16_t* __restrict__ V, int use_lo)
{
  __shared__ uint32_t xt[64][132];    // [n][c-in-half] h|l packed, 33792 B
  __shared__ uint16_t sW[15360];      // Wh slice [320][40] + Wl [64][40]

  int b = blockIdx.x & 7, n0 = (blockIdx.x >> 3) * 64;
  int tid = threadIdx.x, wid = tid >> 6, lane = tid & 63;
  int l15 = lane & 15, quad = lane >> 4;
  int nb = wid * 16;                  // n within tile for this wave

  auto stageW = [&](int ks) {
    const uint16_t* srcH = WhP + (size_t)ks * 12800;
    const uint16_t* srcL = WlP + (size_t)ks * 2560;
#pragma unroll
    for (int i = 0; i < 8; i++) {
      int idx = i * 256 + tid;             // 16B-chunk index, 0..1919
      if (idx < 1920) {
        const uint16_t* g = (idx < 1600) ? (srcH + (size_t)idx * 8)
                                         : (srcL + (size_t)(idx - 1600) * 8);
        async16(g, sW + (size_t)idx * 8);  // dest = uniform base + lane*16
      }
    }
  };
  // transpose one 128-channel half of this block's x slice into xt
  auto transpose = [&](int ch) {
    const float* xb = x + ((size_t)b * NC + ch * 128) * NN + n0;
    int cc = tid >> 4, nw = (tid & 15) << 2;
#pragma unroll
    for (int i = 0; i < 8; i++) {
      int c = cc + 16 * i;                 // 0..127 within half
      float4_ v = *reinterpret_cast<const float4_*>(xb + (size_t)c * NN + nw);
#pragma unroll
      for (int u = 0; u < 4; u++) {
        uint16_t h = f2bf(v[u]);
        uint16_t l = f2bf(v[u] - bf2f(h));
        xt[nw + u][c] = (uint32_t)h | ((uint32_t)l << 16);
      }
    }
  };

  float4_ acc[20];
  for (int m = 0; m < 20; m++) acc[m] = (float4_){0.f, 0.f, 0.f, 0.f};

  stageW(0);                          // in flight under the transpose
  transpose(0);
  __syncthreads();                    // drains vmcnt+lgkm: xt half0 + sW0 ready

  for (int gks = 0; gks < 8; gks++) {
    int ksl = gks & 3;
    // B-frags from xt: 8 packed dwords = h|l of xT[n][ksl*32+quad*8 .. +7]
    const uint32_t* xr = &xt[nb + l15][ksl * 32 + quad * 8];
    uint4_ r0 = *reinterpret_cast<const uint4_*>(xr);
    uint4_ r1 = *reinterpret_cast<const uint4_*>(xr + 4);
    uint4_ H, L;
    H.x = (r0.x & 0xffffu) | (r0.y << 16);
    L.x = (r0.x >> 16)     | (r0.y & 0xffff0000u);
    H.y = (r0.z & 0xffffu) | (r0.w << 16);
    L.y = (r0.z >> 16)     | (r0.w & 0xffff0000u);
    H.z = (r1.x & 0xffffu) | (r1.y << 16);
    L.z = (r1.x >> 16)     | (r1.y & 0xffff0000u);
    H.w = (r1.z & 0xffffu) | (r1.w << 16);
    L.w = (r1.z >> 16)     | (r1.w & 0xffff0000u);
    short8 bh  = __builtin_bit_cast(short8, H);
    short8 blo = __builtin_bit_cast(short8, L);
#pragma unroll
    for (int mt = 0; mt < 20; mt++) {
      short8 ah = ld8(sW + (16 * mt + l15) * 40 + quad * 8);
      acc[mt] = MFMA16(ah, bh, acc[mt]);
      if (mt < 4) {
        short8 al = ld8(sW + 12800 + (16 * mt + l15) * 40 + quad * 8);
        acc[mt] = MFMA16(al, bh, acc[mt]);
      }
      acc[mt] = MFMA16(ah, blo, acc[mt]);  // low-order x part (always on)
    }
    __syncthreads();                  // sW/xt reads retired
    if (gks < 7) {
      stageW(gks + 1);                // single-buffer sW: safe after barrier
      if (gks == 3) transpose(1);     // xt half1; overlaps stage latency
      __syncthreads();                // vmcnt+lgkm drained -> ready
    }
  }

  int n = n0 + wid * 16 + l15;
  for (int mt = 0; mt < 20; mt++) {
    for (int r = 0; r < 4; r++) {
      int row = 16 * mt + quad * 4 + r;
      float v = acc[mt][r];
      if (mt < 2) {
        v = (v + bq[row]) * L2E;      // log2-domain Q
        size_t o = ((size_t)b * NN + n) * ND + row;
        uint16_t h = f2bf(v);
        Qh[o] = h;
        if (use_lo) Ql[o] = f2bf(v - bf2f(h));
      } else if (mt < 4) {
        int rk = row - 32;
        v += bk[rk];
        size_t o = ((size_t)b * NN + n) * ND + rk;
        uint16_t h = f2bf(v);
        Kh[o] = h;
        if (use_lo) Kl[o] = f2bf(v - bf2f(h));
      } else {
        int c = row - 64;
        v += bv[c];
        V[((size_t)b * NC + c) * NN + n] = f2bf(v);
      }
    }
  }
}

// ---------------------------------------------------------------------------
// k_attn: VERBATIM R3/R6 (139-144 us, passed): single-barrier pipeline.
//   512 blocks (8 b x 64 q-tiles of 64), 512 thr = 8 waves, 2 blocks/CU.
//   Per phase j (ONE barrier at the end):
//     heavy (waves 0-3): prefetch K(j+2) regs; QK^T(j+1) -> sP[(j+1)&1];
//                        then PV(j).
//     light (waves 4-7): stage V(j+3) into buf (j+3)&3 (NBUF=4); then PV(j);
//                        vmcnt(8) keeps 2 stages in flight across the barrier.
// ---------------------------------------------------------------------------
__global__ __launch_bounds__(512, 4) void k_attn(
    const uint16_t* __restrict__ Qh, const uint16_t* __restrict__ Ql,
    const uint16_t* __restrict__ Kh, const uint16_t* __restrict__ Kl,
    const uint16_t* __restrict__ V, float* __restrict__ out, int use_lo)
{
  __shared__ uint16_t sV[NBUF][256][KT];  // 64 KB, chunk-swizzled
  __shared__ uint16_t sP[2][4][16][40];   // dbuf P^T [buf][qgroup][q][k]
  __shared__ float sL[QT];

  int bx = blockIdx.x;
  int b = bx & 7;                         // batch <-> XCD affinity
  int q0 = (bx >> 3) * QT;
  int tid = threadIdx.x, wid = tid >> 6, lane = tid & 63;
  int l15 = lane & 15, quad = lane >> 4;
  const size_t qkb = (size_t)b * NN * ND;
  const uint16_t* Vb = V + (size_t)b * NC * NN;
  const bool heavy = (wid < 4);

  int sw = (l15 >> 1) & 3;                // read-side swizzle key

  // ---- light-wave staging state: hoisted incremental pointers ----
  const uint16_t* gp0; const uint16_t* gp1;
  const uint16_t* gp2; const uint16_t* gp3;
  uint32_t off0, off1, off2, off3;
  if (!heavy) {
#define INITGP(i, GP, OFF)                                   \
    { int sl = (wid - 4) * 256 + 64 * i + lane;              \
      int c = sl >> 2;                                       \
      int q2s = (sl & 3) ^ ((sl >> 3) & 3);                  \
      GP = Vb + (size_t)c * NN + q2s * 8;                    \
      OFF = (uint32_t)(((wid - 4) * 4 + i) * 512); }
    INITGP(0, gp0, off0) INITGP(1, gp1, off1)
    INITGP(2, gp2, off2) INITGP(3, gp3, off3)
#undef INITGP
  }
  auto stage = [&](int s) {
    uint16_t* base = &sV[0][0][0] + (size_t)(s & 3) * 8192;
    async16(gp0, base + off0); gp0 += KT;
    async16(gp1, base + off1); gp1 += KT;
    async16(gp2, base + off2); gp2 += KT;
    async16(gp3, base + off3); gp3 += KT;
  };

  float4_ acc[2][4];                      // [c-tile][q-group]
  for (int m = 0; m < 2; m++) for (int n = 0; n < 4; n++)
    acc[m][n] = (float4_){0.f, 0.f, 0.f, 0.f};
  float l_part = 0.f;

  short8 qfh, qfl, kh0, kh1, kl0, kl1;
  const uint16_t* pKh = Kh + qkb + (size_t)l15 * ND + quad * 8;
  const uint16_t* pKl = Kl + qkb + (size_t)l15 * ND + quad * 8;

  // QK^T for key-tile index t, writing sP[sb][wid]
  auto qkt = [&](int sb, short8 h0, short8 h1, short8 lo0, short8 lo1) {
    float4_ S0 = (float4_){0.f, 0.f, 0.f, 0.f}, S1 = S0;
    S0 = MFMA16(h0, qfh, S0);
    S1 = MFMA16(h1, qfh, S1);
    if (use_lo) {
      S0 = MFMA16(lo0, qfh, S0); S0 = MFMA16(h0, qfl, S0);
      S1 = MFMA16(lo1, qfh, S1); S1 = MFMA16(h1, qfl, S1);
    }
    float p0[4], p1[4];
#pragma unroll
    for (int r = 0; r < 4; r++) {
      p0[r] = EXP2(S0[r] - SCB);
      p1[r] = EXP2(S1[r] - SCB);
    }
    l_part += ((p0[0] + p0[1]) + (p0[2] + p0[3])) +
              ((p1[0] + p1[1]) + (p1[2] + p1[3]));
    uint2 w0, w1;
    w0.x = cvtpk(p0[0], p0[1]); w0.y = cvtpk(p0[2], p0[3]);
    w1.x = cvtpk(p1[0], p1[1]); w1.y = cvtpk(p1[2], p1[3]);
    *reinterpret_cast<uint2*>(&sP[sb][wid][l15][4 * quad]) = w0;
    *reinterpret_cast<uint2*>(&sP[sb][wid][l15][16 + 4 * quad]) = w1;
  };

  // ---- prologue ----
  if (heavy) {
    size_t a = qkb + (size_t)(q0 + wid * 16 + l15) * ND + quad * 8;
    qfh = ld8(Qh + a);
    if (use_lo) qfl = ld8(Ql + a);
    // K(0): compute QK^T(0) -> sP[0]
    short8 t0 = ld8(pKh), t1 = ld8(pKh + 512), tl0, tl1;
    if (use_lo) { tl0 = ld8(pKl); tl1 = ld8(pKl + 512); }
    qkt(0, t0, t1, tl0, tl1);
    // K(1) -> current frags (consumed by QK^T(1) in phase 0)
    kh0 = ld8(pKh + 1024); kh1 = ld8(pKh + 1536);
    if (use_lo) { kl0 = ld8(pKl + 1024); kl1 = ld8(pKl + 1536); }
    pKh += 2048; pKl += 2048;             // -> K(2)
    asm volatile("s_waitcnt lgkmcnt(0)" ::: "memory");  // sP[0] visible
  } else {
    stage(0); stage(1); stage(2);
    asm volatile("s_waitcnt vmcnt(8)" ::: "memory");    // stage(0) landed
  }
  fbar();                                 // sP[0] + sV buf0 ready

  for (int j = 0; j < NN / KT; j++) {
    int buf = j & 3;
    int pb = j & 1;
    if (heavy) {
      short8 nh0, nh1, nl0, nl1;
      if (j < NN / KT - 2) {              // prefetch K(j+2)
        nh0 = ld8(pKh); nh1 = ld8(pKh + 512);
        if (use_lo) { nl0 = ld8(pKl); nl1 = ld8(pKl + 512); }
        pKh += 1024; pKl += 1024;
      }
      if (j < NN / KT - 1)                // QK^T(j+1) -> sP[(j+1)&1]
        qkt(pb ^ 1, kh0, kh1, kl0, kl1);
      kh0 = nh0; kh1 = nh1;
      if (use_lo) { kl0 = nl0; kl1 = nl1; }
    } else {
      if (j < NN / KT - 3) stage(j + 3);  // buf (j+3)&3: readers at j-1 done
    }
    // PV(j): all waves, 32 channels x 64 q
    short8 bfP[4];
#pragma unroll
    for (int qt = 0; qt < 4; qt++)
      bfP[qt] = ld8(&sP[pb][qt][l15][quad * 8]);
#pragma unroll
    for (int mt = 0; mt < 2; mt++) {
      short8 af = ld8(&sV[buf][wid * 32 + 16 * mt + l15][(quad ^ sw) * 8]);
#pragma unroll
      for (int qt = 0; qt < 4; qt++)
        acc[mt][qt] = MFMA16(af, bfP[qt], acc[mt][qt]);
    }
    if (!heavy) {
      if (j < NN / KT - 3)
        asm volatile("s_waitcnt vmcnt(8)" ::: "memory");  // stage(j+1) landed
      else
        asm volatile("s_waitcnt vmcnt(0)" ::: "memory");  // tail drain
    }
    // all LDS ops (sP write + PV reads) retired before anyone reuses buffers
    asm volatile("s_waitcnt lgkmcnt(0)" ::: "memory");
    fbar();
  }

  if (heavy) {
    float l_tot = l_part;
    l_tot += __shfl_xor(l_tot, 16);
    l_tot += __shfl_xor(l_tot, 32);
    if (quad == 0) sL[wid * 16 + l15] = l_tot;
  }
  __syncthreads();
  float linv[4];
  for (int qt = 0; qt < 4; qt++) linv[qt] = 1.0f / sL[qt * 16 + l15];
  for (int mt = 0; mt < 2; mt++)
    for (int qt = 0; qt < 4; qt++)
      for (int r = 0; r < 4; r++) {
        int c = wid * 32 + 16 * mt + quad * 4 + r;
        int q = q0 + qt * 16 + l15;
        out[((size_t)(b * NC + c)) * NN + q] = acc[mt][qt][r] * linv[qt];
      }
}

// ---------------------------------------------------------------------------
extern "C" void kernel_launch(void* const* d_in, const int* in_sizes, int n_in,
                              void* d_out, int out_size, void* d_ws, size_t ws_size,
                              hipStream_t stream)
{
  const float* x  = (const float*)d_in[0];
  const float* wq = (const float*)d_in[1];
  const float* bq = (const float*)d_in[2];
  const float* wk = (const float*)d_in[3];
  const float* bk = (const float*)d_in[4];
  const float* wv = (const float*)d_in[5];
  const float* bv = (const float*)d_in[6];
  float* out = (float*)d_out;

  const size_t szWh = (size_t)8 * 320 * 40 * 2;   // padded slice layout
  const size_t szWl = (size_t)8 * 64 * 40 * 2;
  const size_t szQK = (size_t)NB * NN * ND * 2;
  const size_t szV  = (size_t)NB * NC * NN * 2;
  size_t needB = szWh + szWl + 4 * szQK + szV;
  int use_lo = ws_size >= needB;

  char* p = (char*)d_ws;
  uint16_t* WhP = (uint16_t*)p; p += szWh;
  uint16_t* WlP = (uint16_t*)p; p += szWl;
  uint16_t* Qh = (uint16_t*)p; p += szQK;
  uint16_t* Ql = use_lo ? (uint16_t*)p : Qh; if (use_lo) p += szQK;
  uint16_t* Kh = (uint16_t*)p; p += szQK;
  uint16_t* Kl = use_lo ? (uint16_t*)p : Kh; if (use_lo) p += szQK;
  uint16_t* Vw = (uint16_t*)p;

  hipLaunchKernelGGL(k_prep, dim3(320), dim3(256), 0, stream,
                     wq, wk, wv, WhP, WlP);
  hipLaunchKernelGGL(k_qkv, dim3(512), dim3(256), 0, stream,
                     x, WhP, WlP, bq, bk, bv, Qh, Ql, Kh, Kl, Vw, use_lo);
  hipLaunchKernelGGL(k_attn, dim3(512), dim3(512), 0, stream,
                     Qh, Ql, Kh, Kl, Vw, out, use_lo);
}